// Round 8
// baseline (544.503 us; speedup 1.0000x reference)
//
#include <hip/hip_runtime.h>
#include <hip/hip_bf16.h>

typedef __bf16 bf16x8 __attribute__((ext_vector_type(8)));
typedef __bf16 bf16x2 __attribute__((ext_vector_type(2)));
typedef float  f32x4  __attribute__((ext_vector_type(4)));

#define MFMA16(a,b,c) __builtin_amdgcn_mfma_f32_16x16x32_bf16((a),(b),(c),0,0,0)

// ---------------- setup: weight prepack + hv->bf16 + degree count, one dispatch -------
// wmsg_bf : [T][256][384]  = W_msg
// wrz_bf  : [T][256][384]  row o = [Whh[o][0:128] | Wih[o][0:256]]
// win_bf  : [T][128][256]  row j = Wih[256+j]
// whn_bf  : [T][128][128]  row j = Whh[256+j]
__global__ void k_setup(const float* __restrict__ wmsg, const float* __restrict__ wih,
                        const float* __restrict__ whh, const float* __restrict__ hv,
                        const int* __restrict__ dst,
                        __bf16* __restrict__ o_msg, __bf16* __restrict__ o_rz,
                        __bf16* __restrict__ o_in, __bf16* __restrict__ o_hn,
                        __bf16* __restrict__ hv_bf, int* __restrict__ degi,
                        int nb_pre, int nb_hv, int hv8, int E) {
    const int C1 = 2 * 256 * 384;
    const int C2 = C1 + 2 * 256 * 384;
    const int C3 = C2 + 2 * 128 * 256;
    const int C4 = C3 + 2 * 128 * 128;
    int b = blockIdx.x;
    if (b < nb_pre) {
        int i = b * 256 + threadIdx.x;
        if (i >= C4) return;
        if (i < C1) {
            o_msg[i] = (__bf16)wmsg[i];
        } else if (i < C2) {
            int p = i - C1;
            int t = p / 98304, rem = p % 98304;
            int o = rem / 384, c = rem % 384;
            float v = (c < 128) ? whh[t * 49152 + o * 128 + c]
                                : wih[t * 98304 + o * 256 + (c - 128)];
            o_rz[p] = (__bf16)v;
        } else if (i < C3) {
            int p = i - C2;
            int t = p / 32768, rem = p % 32768;
            int j = rem / 256, k = rem % 256;
            o_in[p] = (__bf16)wih[t * 98304 + (256 + j) * 256 + k];
        } else {
            int p = i - C3;
            int t = p / 16384, rem = p % 16384;
            int j = rem / 128, k = rem % 128;
            o_hn[p] = (__bf16)whh[t * 49152 + (256 + j) * 128 + k];
        }
    } else if (b < nb_pre + nb_hv) {
        int i = (b - nb_pre) * 256 + threadIdx.x;
        if (i >= hv8) return;
        const float4* p = (const float4*)(hv + (size_t)i * 8);
        float4 a = p[0], c = p[1];
        bf16x8 o;
        o[0] = (__bf16)a.x; o[1] = (__bf16)a.y; o[2] = (__bf16)a.z; o[3] = (__bf16)a.w;
        o[4] = (__bf16)c.x; o[5] = (__bf16)c.y; o[6] = (__bf16)c.z; o[7] = (__bf16)c.w;
        *(bf16x8*)(hv_bf + (size_t)i * 8) = o;
    } else {
        int e = (b - nb_pre - nb_hv) * 256 + threadIdx.x;
        if (e < E) atomicAdd(&degi[dst[e]], 1);
    }
}

// ---------------- CSR build ----------------
__global__ void k_alloc(const int* __restrict__ degi, int* __restrict__ off,
                        int* __restrict__ cnt, int* __restrict__ counter, int N) {
    int i = blockIdx.x * 256 + threadIdx.x;
    int lane = (int)threadIdx.x & 63;
    int v = (i < N) ? degi[i] : 0;
    int incl = v;
    #pragma unroll
    for (int d = 1; d < 64; d <<= 1) {
        int t = __shfl_up(incl, d, 64);
        if (lane >= d) incl += t;
    }
    int base = 0;
    if (lane == 63) base = atomicAdd(counter, incl);
    base = __shfl(base, 63, 64);
    if (i < N) { off[i] = base + incl - v; cnt[i] = 0; }
}

__global__ void k_bucket(const int* __restrict__ src, const int* __restrict__ dst,
                         const int* __restrict__ off, int* __restrict__ cnt,
                         int2* __restrict__ pairs, int E) {
    int e = blockIdx.x * 256 + threadIdx.x;
    if (e < E) {
        int d = dst[e];
        int p = off[d] + atomicAdd(&cnt[d], 1);
        pairs[p] = make_int2(src[e], e);
    }
}

// ---------------- fused round: gather prologue + 3.5 GEMMs + GRU epilogue ----------
// ROUND==1: gather mean(hv_rd[src]) AND mean(he[eid]) into xs; store he_mean; write
//           bf16(hv_new) to hv_wr (SEPARATE buffer -> no read/write race across blocks).
// ROUND==2: gather mean(hv_rd[src]); he_mean from global; no bf16 write.
// xs = [hv(128) | hsrc(128) | he(128)]; after GEMM1 cols [128,384) overlaid with 'a'.
template<int ROUND>
__launch_bounds__(256, 4)
__global__ void k_fused(
    const float* __restrict__ hv_hold,     // [N,128] f32 (GRU hold; may alias hv_out)
    const __bf16* __restrict__ hv_rd,      // [N,128] bf16 gather/tile source (read-only!)
    __bf16* __restrict__ hv_wr,            // [N,128] bf16 out (ROUND==1 only)
    const float* __restrict__ he,          // [E,128] f32 (ROUND==1 only)
    __bf16* __restrict__ he_mean_g,        // [N,128] bf16 (out in R1, in in R2)
    const int2* __restrict__ pairs,
    const int* __restrict__ off, const int* __restrict__ degi,
    const __bf16* __restrict__ Wmsg,       // [256,384]
    const float* __restrict__ bmsg,        // [256]
    const __bf16* __restrict__ Wrz,        // [256,384]
    const __bf16* __restrict__ Win,        // [128,256]
    const __bf16* __restrict__ Whn,        // [128,128]
    const float* __restrict__ bih,         // [384]
    const float* __restrict__ bhh,         // [384]
    float* __restrict__ hv_out, int N)
{
    __shared__ __bf16 xs[32][392];   // 384 + 8 pad; [128,384) reused for 'a' after GEMM1

    const int tid  = threadIdx.x;
    const int m0   = blockIdx.x * 32;
    const int wave = tid >> 6;
    const int lane = tid & 63;

    // ---- xs cols [0,128): hv_rd rows ----
    for (int idx = tid; idx < 32 * 16; idx += 256) {
        int row = idx >> 4, c8 = (idx & 15) * 8;
        int node = m0 + row;
        bf16x8 v = {};
        if (node < N) v = *(const bf16x8*)(hv_rd + (size_t)node * 128 + c8);
        *(bf16x8*)&xs[row][c8] = v;
    }
    // ---- ROUND 2: xs cols [256,384) <- he_mean_g ----
    if (ROUND == 2) {
        for (int idx = tid; idx < 32 * 16; idx += 256) {
            int row = idx >> 4, c8 = (idx & 15) * 8;
            int node = m0 + row;
            bf16x8 v = {};
            if (node < N) v = *(const bf16x8*)(he_mean_g + (size_t)node * 128 + c8);
            *(bf16x8*)&xs[row][256 + c8] = v;
        }
    }

    // ---- gather prologue: wave handles rows [wave*8, wave*8+8) ----
    for (int s = 0; s < 8; ++s) {
        int row  = wave * 8 + s;
        int node = m0 + row;
        if (node < N) {
            int beg = off[node], deg = degi[node];
            int end = beg + deg;
            float h0x=0.f,h0y=0.f,h1x=0.f,h1y=0.f,h2x=0.f,h2y=0.f,h3x=0.f,h3y=0.f;
            float e0x=0.f,e0y=0.f,e1x=0.f,e1y=0.f,e2x=0.f,e2y=0.f,e3x=0.f,e3y=0.f;
            int p = beg;
            for (; p + 3 < end; p += 4) {
                int2 a = pairs[p], b = pairs[p+1], c = pairs[p+2], d = pairs[p+3];
                bf16x2 v0 = *(const bf16x2*)(hv_rd + (size_t)a.x * 128 + lane * 2);
                bf16x2 v1 = *(const bf16x2*)(hv_rd + (size_t)b.x * 128 + lane * 2);
                bf16x2 v2 = *(const bf16x2*)(hv_rd + (size_t)c.x * 128 + lane * 2);
                bf16x2 v3 = *(const bf16x2*)(hv_rd + (size_t)d.x * 128 + lane * 2);
                h0x += (float)v0[0]; h0y += (float)v0[1];
                h1x += (float)v1[0]; h1y += (float)v1[1];
                h2x += (float)v2[0]; h2y += (float)v2[1];
                h3x += (float)v3[0]; h3y += (float)v3[1];
                if (ROUND == 1) {
                    float2 w0 = *(const float2*)(he + (size_t)a.y * 128 + lane * 2);
                    float2 w1 = *(const float2*)(he + (size_t)b.y * 128 + lane * 2);
                    float2 w2 = *(const float2*)(he + (size_t)c.y * 128 + lane * 2);
                    float2 w3 = *(const float2*)(he + (size_t)d.y * 128 + lane * 2);
                    e0x += w0.x; e0y += w0.y; e1x += w1.x; e1y += w1.y;
                    e2x += w2.x; e2y += w2.y; e3x += w3.x; e3y += w3.y;
                }
            }
            for (; p < end; ++p) {
                int2 a = pairs[p];
                bf16x2 v0 = *(const bf16x2*)(hv_rd + (size_t)a.x * 128 + lane * 2);
                h0x += (float)v0[0]; h0y += (float)v0[1];
                if (ROUND == 1) {
                    float2 w0 = *(const float2*)(he + (size_t)a.y * 128 + lane * 2);
                    e0x += w0.x; e0y += w0.y;
                }
            }
            float sc = 1.0f / fmaxf((float)deg, 1.0f);
            bf16x2 oh; oh[0] = (__bf16)((h0x+h1x+h2x+h3x) * sc);
            oh[1] = (__bf16)((h0y+h1y+h2y+h3y) * sc);
            *(bf16x2*)&xs[row][128 + lane * 2] = oh;
            if (ROUND == 1) {
                bf16x2 oe; oe[0] = (__bf16)((e0x+e1x+e2x+e3x) * sc);
                oe[1] = (__bf16)((e0y+e1y+e2y+e3y) * sc);
                *(bf16x2*)&xs[row][256 + lane * 2] = oe;
                *(bf16x2*)(he_mean_g + (size_t)node * 128 + lane * 2) = oe;
            }
        } else {
            bf16x2 z = {};
            *(bf16x2*)&xs[row][128 + lane * 2] = z;
            if (ROUND == 1) *(bf16x2*)&xs[row][256 + lane * 2] = z;
        }
    }
    __syncthreads();

    const int lr = lane & 15;
    const int lk = lane >> 4;

    // ---- GEMM1: a = x @ Wmsg^T ----
    f32x4 acc1[2][4] = {};
    #pragma unroll 2
    for (int k0 = 0; k0 < 384; k0 += 32) {
        bf16x8 a0 = *(const bf16x8*)&xs[lr][k0 + lk * 8];
        bf16x8 a1 = *(const bf16x8*)&xs[16 + lr][k0 + lk * 8];
        #pragma unroll
        for (int c = 0; c < 4; ++c) {
            const __bf16* wp = Wmsg + (size_t)(wave * 64 + c * 16 + lr) * 384 + k0 + lk * 8;
            bf16x8 b = *(const bf16x8*)wp;
            acc1[0][c] = MFMA16(a0, b, acc1[0][c]);
            acc1[1][c] = MFMA16(a1, b, acc1[1][c]);
        }
    }
    __syncthreads();    // all waves done reading xs[*][128..383] before overlay write

    // ---- GEMM_hn: hn = hv @ Whn^T (cols [0,128), disjoint from overlay) ----
    f32x4 acchn[2][2] = {};
    #pragma unroll
    for (int k0 = 0; k0 < 128; k0 += 32) {
        bf16x8 a0 = *(const bf16x8*)&xs[lr][k0 + lk * 8];
        bf16x8 a1 = *(const bf16x8*)&xs[16 + lr][k0 + lk * 8];
        #pragma unroll
        for (int q = 0; q < 2; ++q) {
            int o = wave * 32 + q * 16 + lr;
            bf16x8 b = *(const bf16x8*)(Whn + (size_t)o * 128 + k0 + lk * 8);
            acchn[0][q] = MFMA16(a0, b, acchn[0][q]);
            acchn[1][q] = MFMA16(a1, b, acchn[1][q]);
        }
    }

    // ---- write a (+bias) into xs[*][128 + n] ----
    #pragma unroll
    for (int mf = 0; mf < 2; ++mf) {
        #pragma unroll
        for (int c = 0; c < 4; ++c) {
            int n = wave * 64 + c * 16 + lr;
            float bias = bmsg[n];
            #pragma unroll
            for (int r = 0; r < 4; ++r) {
                int m = mf * 16 + lk * 4 + r;
                xs[m][128 + n] = (__bf16)(acc1[mf][c][r] + bias);
            }
        }
    }
    __syncthreads();

    // ---- GEMM_rz: rz = [hv|a] @ Wrz^T over K=384 ----
    f32x4 accrz[2][4] = {};
    #pragma unroll 2
    for (int k0 = 0; k0 < 384; k0 += 32) {
        bf16x8 a0 = *(const bf16x8*)&xs[lr][k0 + lk * 8];
        bf16x8 a1 = *(const bf16x8*)&xs[16 + lr][k0 + lk * 8];
        #pragma unroll
        for (int q = 0; q < 4; ++q) {
            int o = (q >> 1) * 128 + wave * 32 + (q & 1) * 16 + lr;
            bf16x8 b = *(const bf16x8*)(Wrz + (size_t)o * 384 + k0 + lk * 8);
            accrz[0][q] = MFMA16(a0, b, accrz[0][q]);
            accrz[1][q] = MFMA16(a1, b, accrz[1][q]);
        }
    }

    // ---- GEMM_in: in = a @ Win^T over K=256 ----
    f32x4 accin[2][2] = {};
    #pragma unroll 2
    for (int k0 = 0; k0 < 256; k0 += 32) {
        bf16x8 a0 = *(const bf16x8*)&xs[lr][128 + k0 + lk * 8];
        bf16x8 a1 = *(const bf16x8*)&xs[16 + lr][128 + k0 + lk * 8];
        #pragma unroll
        for (int q = 0; q < 2; ++q) {
            int o = wave * 32 + q * 16 + lr;
            bf16x8 b = *(const bf16x8*)(Win + (size_t)o * 256 + k0 + lk * 8);
            accin[0][q] = MFMA16(a0, b, accin[0][q]);
            accin[1][q] = MFMA16(a1, b, accin[1][q]);
        }
    }

    // ---- GRU epilogue ----
    #pragma unroll
    for (int mf = 0; mf < 2; ++mf) {
        #pragma unroll
        for (int j = 0; j < 2; ++j) {
            int hcol = wave * 32 + j * 16 + lr;
            float brz_r = bih[hcol]       + bhh[hcol];
            float brz_z = bih[128 + hcol] + bhh[128 + hcol];
            float b_in  = bih[256 + hcol];
            float b_hn  = bhh[256 + hcol];
            #pragma unroll
            for (int r = 0; r < 4; ++r) {
                int m = mf * 16 + lk * 4 + r;
                int node = m0 + m;
                if (node < N) {
                    float rg = 1.f / (1.f + __expf(-(accrz[mf][0 + j][r] + brz_r)));
                    float zg = 1.f / (1.f + __expf(-(accrz[mf][2 + j][r] + brz_z)));
                    float ng = tanhf(accin[mf][j][r] + b_in + rg * (acchn[mf][j][r] + b_hn));
                    float hold = hv_hold[(size_t)node * 128 + hcol];
                    float hnew = (1.f - zg) * ng + zg * hold;
                    hv_out[(size_t)node * 128 + hcol] = hnew;
                    if (ROUND == 1) hv_wr[(size_t)node * 128 + hcol] = (__bf16)hnew;
                }
            }
        }
    }
}

extern "C" void kernel_launch(void* const* d_in, const int* in_sizes, int n_in,
                              void* d_out, int out_size, void* d_ws, size_t ws_size,
                              hipStream_t stream)
{
    const float* hv   = (const float*)d_in[0];
    const float* he   = (const float*)d_in[1];
    const int*   src  = (const int*)d_in[2];
    const int*   dst  = (const int*)d_in[3];
    const float* Wmsg = (const float*)d_in[4];
    const float* bmsg = (const float*)d_in[5];
    const float* Wih  = (const float*)d_in[6];
    const float* Whh  = (const float*)d_in[7];
    const float* bih  = (const float*)d_in[8];
    const float* bhh  = (const float*)d_in[9];

    const int H = 128;
    const int N = in_sizes[0] / H;
    const int E = in_sizes[2];

    // ---- workspace layout (~46 MB) ----
    char* w = (char*)d_ws;
    __bf16* he_mean = (__bf16*)w;  w += (size_t)N * H * 2;
    __bf16* hv_bfA  = (__bf16*)w;  w += (size_t)N * H * 2;   // bf16(hv_in), round-1 source
    __bf16* hv_bfB  = (__bf16*)w;  w += (size_t)N * H * 2;   // bf16(hv after round 1)
    int* degi    = (int*)w;  w += (size_t)N * 4;
    int* counter = (int*)w;  w += 4;
    int* off     = (int*)w;  w += (size_t)N * 4;
    int* cnt     = (int*)w;  w += (size_t)N * 4;
    w = (char*)(((uintptr_t)w + 15) & ~(uintptr_t)15);
    int2* pairs  = (int2*)w; w += (size_t)E * 8;
    __bf16* wmsg_bf = (__bf16*)w;                       // [2][256][384]
    __bf16* wrz_bf  = wmsg_bf + 2 * 256 * 384;          // [2][256][384]
    __bf16* win_bf  = wrz_bf  + 2 * 256 * 384;          // [2][128][256]
    __bf16* whn_bf  = win_bf  + 2 * 128 * 256;          // [2][128][128]

    hipMemsetAsync(degi, 0, ((size_t)N + 1) * 4, stream);   // degi + counter

    const int prepack_total = 2*256*384 + 2*256*384 + 2*128*256 + 2*128*128;
    const int hv8    = N * H / 8;
    const int nb_pre = (prepack_total + 255) / 256;
    const int nb_hv  = (hv8 + 255) / 256;
    const int nb_deg = (E + 255) / 256;
    k_setup<<<nb_pre + nb_hv + nb_deg, 256, 0, stream>>>(
        Wmsg, Wih, Whh, hv, dst,
        wmsg_bf, wrz_bf, win_bf, whn_bf, hv_bfA, degi,
        nb_pre, nb_hv, hv8, E);

    k_alloc<<<(N + 255) / 256, 256, 0, stream>>>(degi, off, cnt, counter, N);
    k_bucket<<<(E + 255) / 256, 256, 0, stream>>>(src, dst, off, cnt, pairs, E);

    float* out = (float*)d_out;
    const int nb_f = (N + 31) / 32;

    // round 1: read hv_bfA, write bf16 new state to hv_bfB (disjoint -> race-free)
    k_fused<1><<<nb_f, 256, 0, stream>>>(
        hv, hv_bfA, hv_bfB, he, he_mean, pairs, off, degi,
        wmsg_bf, bmsg, wrz_bf, win_bf, whn_bf, bih, bhh, out, N);

    // round 2: read hv_bfB
    k_fused<2><<<nb_f, 256, 0, stream>>>(
        out, hv_bfB, nullptr, nullptr, he_mean, pairs, off, degi,
        wmsg_bf + (size_t)256 * 384, bmsg + 256,
        wrz_bf + (size_t)256 * 384, win_bf + (size_t)128 * 256, whn_bf + (size_t)128 * 128,
        bih + 384, bhh + 384, out, N);
}

// Round 9
// 462.781 us; speedup vs baseline: 1.1766x; 1.1766x over previous
//
#include <hip/hip_runtime.h>
#include <hip/hip_bf16.h>

typedef __bf16 bf16x8 __attribute__((ext_vector_type(8)));
typedef __bf16 bf16x2 __attribute__((ext_vector_type(2)));
typedef float  f32x4  __attribute__((ext_vector_type(4)));

#define MFMA16(a,b,c) __builtin_amdgcn_mfma_f32_16x16x32_bf16((a),(b),(c),0,0,0)

// ---------------- setup: weight prepack + hv->bf16 + degree count, one dispatch -------
__global__ void k_setup(const float* __restrict__ wmsg, const float* __restrict__ wih,
                        const float* __restrict__ whh, const float* __restrict__ hv,
                        const int* __restrict__ dst,
                        __bf16* __restrict__ o_msg, __bf16* __restrict__ o_rz,
                        __bf16* __restrict__ o_in, __bf16* __restrict__ o_hn,
                        __bf16* __restrict__ hv_bf, int* __restrict__ degi,
                        int nb_pre, int nb_hv, int hv8, int E) {
    const int C1 = 2 * 256 * 384;
    const int C2 = C1 + 2 * 256 * 384;
    const int C3 = C2 + 2 * 128 * 256;
    const int C4 = C3 + 2 * 128 * 128;
    int b = blockIdx.x;
    if (b < nb_pre) {
        int i = b * 256 + threadIdx.x;
        if (i >= C4) return;
        if (i < C1) {
            o_msg[i] = (__bf16)wmsg[i];
        } else if (i < C2) {
            int p = i - C1;
            int t = p / 98304, rem = p % 98304;
            int o = rem / 384, c = rem % 384;
            float v = (c < 128) ? whh[t * 49152 + o * 128 + c]
                                : wih[t * 98304 + o * 256 + (c - 128)];
            o_rz[p] = (__bf16)v;
        } else if (i < C3) {
            int p = i - C2;
            int t = p / 32768, rem = p % 32768;
            int j = rem / 256, k = rem % 256;
            o_in[p] = (__bf16)wih[t * 98304 + (256 + j) * 256 + k];
        } else {
            int p = i - C3;
            int t = p / 16384, rem = p % 16384;
            int j = rem / 128, k = rem % 128;
            o_hn[p] = (__bf16)whh[t * 49152 + (256 + j) * 128 + k];
        }
    } else if (b < nb_pre + nb_hv) {
        int i = (b - nb_pre) * 256 + threadIdx.x;
        if (i >= hv8) return;
        const float4* p = (const float4*)(hv + (size_t)i * 8);
        float4 a = p[0], c = p[1];
        bf16x8 o;
        o[0] = (__bf16)a.x; o[1] = (__bf16)a.y; o[2] = (__bf16)a.z; o[3] = (__bf16)a.w;
        o[4] = (__bf16)c.x; o[5] = (__bf16)c.y; o[6] = (__bf16)c.z; o[7] = (__bf16)c.w;
        *(bf16x8*)(hv_bf + (size_t)i * 8) = o;
    } else {
        int e = (b - nb_pre - nb_hv) * 256 + threadIdx.x;
        if (e < E) atomicAdd(&degi[dst[e]], 1);
    }
}

// ---------------- CSR build ----------------
__global__ void k_alloc(const int* __restrict__ degi, int* __restrict__ off,
                        int* __restrict__ cnt, int* __restrict__ counter, int N) {
    int i = blockIdx.x * 256 + threadIdx.x;
    int lane = (int)threadIdx.x & 63;
    int v = (i < N) ? degi[i] : 0;
    int incl = v;
    #pragma unroll
    for (int d = 1; d < 64; d <<= 1) {
        int t = __shfl_up(incl, d, 64);
        if (lane >= d) incl += t;
    }
    int base = 0;
    if (lane == 63) base = atomicAdd(counter, incl);
    base = __shfl(base, 63, 64);
    if (i < N) { off[i] = base + incl - v; cnt[i] = 0; }
}

__global__ void k_bucket(const int* __restrict__ src, const int* __restrict__ dst,
                         const int* __restrict__ off, int* __restrict__ cnt,
                         int2* __restrict__ pairs, int E) {
    int e = blockIdx.x * 256 + threadIdx.x;
    if (e < E) {
        int d = dst[e];
        int p = off[d] + atomicAdd(&cnt[d], 1);
        pairs[p] = make_int2(src[e], e);
    }
}

// ---------------- round-1 gather: mean(hv_bf[src]) and mean(he[eid]) ----------------
__global__ void k_gather_both(const __bf16* __restrict__ hv_bf, const float* __restrict__ he,
                              const int2* __restrict__ pairs,
                              const int* __restrict__ off, const int* __restrict__ degi,
                              __bf16* __restrict__ hsrc_mean, __bf16* __restrict__ he_mean,
                              int N) {
    int node = blockIdx.x * 4 + ((int)threadIdx.x >> 6);
    if (node >= N) return;
    int lane = (int)threadIdx.x & 63;
    int beg = off[node], deg = degi[node];
    int end = beg + deg;
    float h0x=0.f,h0y=0.f,h1x=0.f,h1y=0.f,h2x=0.f,h2y=0.f,h3x=0.f,h3y=0.f;
    float e0x=0.f,e0y=0.f,e1x=0.f,e1y=0.f,e2x=0.f,e2y=0.f,e3x=0.f,e3y=0.f;
    int p = beg;
    for (; p + 3 < end; p += 4) {
        int2 a = pairs[p], b = pairs[p+1], c = pairs[p+2], d = pairs[p+3];
        bf16x2 v0 = *(const bf16x2*)(hv_bf + (size_t)a.x * 128 + lane * 2);
        bf16x2 v1 = *(const bf16x2*)(hv_bf + (size_t)b.x * 128 + lane * 2);
        bf16x2 v2 = *(const bf16x2*)(hv_bf + (size_t)c.x * 128 + lane * 2);
        bf16x2 v3 = *(const bf16x2*)(hv_bf + (size_t)d.x * 128 + lane * 2);
        float2 w0 = *(const float2*)(he + (size_t)a.y * 128 + lane * 2);
        float2 w1 = *(const float2*)(he + (size_t)b.y * 128 + lane * 2);
        float2 w2 = *(const float2*)(he + (size_t)c.y * 128 + lane * 2);
        float2 w3 = *(const float2*)(he + (size_t)d.y * 128 + lane * 2);
        h0x += (float)v0[0]; h0y += (float)v0[1]; h1x += (float)v1[0]; h1y += (float)v1[1];
        h2x += (float)v2[0]; h2y += (float)v2[1]; h3x += (float)v3[0]; h3y += (float)v3[1];
        e0x += w0.x; e0y += w0.y; e1x += w1.x; e1y += w1.y;
        e2x += w2.x; e2y += w2.y; e3x += w3.x; e3y += w3.y;
    }
    for (; p < end; ++p) {
        int2 a = pairs[p];
        bf16x2 v0 = *(const bf16x2*)(hv_bf + (size_t)a.x * 128 + lane * 2);
        float2 w0 = *(const float2*)(he + (size_t)a.y * 128 + lane * 2);
        h0x += (float)v0[0]; h0y += (float)v0[1];
        e0x += w0.x; e0y += w0.y;
    }
    float s = 1.0f / fmaxf((float)deg, 1.0f);
    bf16x2 oh; oh[0] = (__bf16)((h0x+h1x+h2x+h3x) * s); oh[1] = (__bf16)((h0y+h1y+h2y+h3y) * s);
    bf16x2 oe; oe[0] = (__bf16)((e0x+e1x+e2x+e3x) * s); oe[1] = (__bf16)((e0y+e1y+e2y+e3y) * s);
    *(bf16x2*)(hsrc_mean + (size_t)node * 128 + lane * 2) = oh;
    *(bf16x2*)(he_mean   + (size_t)node * 128 + lane * 2) = oe;
}

// ---------------- round-2 gather: mean(hv_bf[src]) only ----------------
__global__ void k_gather_hv(const __bf16* __restrict__ hv_bf, const int2* __restrict__ pairs,
                            const int* __restrict__ off, const int* __restrict__ degi,
                            __bf16* __restrict__ hsrc_mean, int N) {
    int node = blockIdx.x * 4 + ((int)threadIdx.x >> 6);
    if (node >= N) return;
    int lane = (int)threadIdx.x & 63;
    int beg = off[node], deg = degi[node];
    int end = beg + deg;
    float a0x=0.f,a0y=0.f,a1x=0.f,a1y=0.f,a2x=0.f,a2y=0.f,a3x=0.f,a3y=0.f;
    int p = beg;
    for (; p + 3 < end; p += 4) {
        int2 pa = pairs[p], pb = pairs[p+1], pc = pairs[p+2], pd = pairs[p+3];
        bf16x2 v0 = *(const bf16x2*)(hv_bf + (size_t)pa.x * 128 + lane * 2);
        bf16x2 v1 = *(const bf16x2*)(hv_bf + (size_t)pb.x * 128 + lane * 2);
        bf16x2 v2 = *(const bf16x2*)(hv_bf + (size_t)pc.x * 128 + lane * 2);
        bf16x2 v3 = *(const bf16x2*)(hv_bf + (size_t)pd.x * 128 + lane * 2);
        a0x += (float)v0[0]; a0y += (float)v0[1]; a1x += (float)v1[0]; a1y += (float)v1[1];
        a2x += (float)v2[0]; a2y += (float)v2[1]; a3x += (float)v3[0]; a3y += (float)v3[1];
    }
    for (; p < end; ++p) {
        int2 pa = pairs[p];
        bf16x2 v0 = *(const bf16x2*)(hv_bf + (size_t)pa.x * 128 + lane * 2);
        a0x += (float)v0[0]; a0y += (float)v0[1];
    }
    float s = 1.0f / fmaxf((float)deg, 1.0f);
    bf16x2 o; o[0] = (__bf16)((a0x+a1x+a2x+a3x) * s); o[1] = (__bf16)((a0y+a1y+a2y+a3y) * s);
    *(bf16x2*)(hsrc_mean + (size_t)node * 128 + lane * 2) = o;
}

// ---------------- fused round, BM=64 (4 waves / 256 thr) ----------------
// xs = [hv(128) | hsrc(128) | he(128)] for 64 rows; cols [128,384) overlaid with 'a'.
// GEMM1: wave w -> cols [w*64, w*64+64); gate GEMMs: wave w -> hcols [w*32, w*32+32).
template<bool WRITE_BF>
__launch_bounds__(256, 2)
__global__ void k_fused_round(
    const float* __restrict__ hv_hold,     // [N,128] f32 (GRU hold; may alias hv_out)
    __bf16* __restrict__ hv_bf,            // [N,128] bf16 (xs source; epilogue-updated if WRITE_BF)
    const __bf16* __restrict__ hsrc_mean,  // [N,128] bf16
    const __bf16* __restrict__ he_mean,    // [N,128] bf16
    const __bf16* __restrict__ Wmsg,       // [256,384]
    const float* __restrict__ bmsg,        // [256]
    const __bf16* __restrict__ Wrz,        // [256,384]
    const __bf16* __restrict__ Win,        // [128,256]
    const __bf16* __restrict__ Whn,        // [128,128]
    const float* __restrict__ bih,         // [384]
    const float* __restrict__ bhh,         // [384]
    float* __restrict__ hv_out, int N)
{
    __shared__ __bf16 xs[64][392];   // 384 + 8 pad; [128,384) reused for 'a' after GEMM1

    const int tid = threadIdx.x;
    const int m0  = blockIdx.x * 64;

    // ---- build x = [hv_bf | hsrc_mean | he_mean] ----
    for (int idx = tid; idx < 64 * 48; idx += 256) {
        int row = idx / 48;
        int c   = idx - row * 48;
        int part = c >> 4;
        int c8   = (c & 15) * 8;
        int node = m0 + row;
        const __bf16* base = (part == 0) ? hv_bf : ((part == 1) ? hsrc_mean : he_mean);
        bf16x8 v = {};
        if (node < N) v = *(const bf16x8*)(base + (size_t)node * 128 + c8);
        *(bf16x8*)&xs[row][part * 128 + c8] = v;
    }
    __syncthreads();

    const int wave = tid >> 6;
    const int lane = tid & 63;
    const int lr = lane & 15;
    const int lk = lane >> 4;

    // ---- GEMM1: a = x @ Wmsg^T (wave w: cols [w*64, w*64+64), all 64 rows) ----
    f32x4 acc1[4][4] = {};
    #pragma unroll 2
    for (int k0 = 0; k0 < 384; k0 += 32) {
        bf16x8 a0 = *(const bf16x8*)&xs[lr][k0 + lk * 8];
        bf16x8 a1 = *(const bf16x8*)&xs[16 + lr][k0 + lk * 8];
        bf16x8 a2 = *(const bf16x8*)&xs[32 + lr][k0 + lk * 8];
        bf16x8 a3 = *(const bf16x8*)&xs[48 + lr][k0 + lk * 8];
        #pragma unroll
        for (int c = 0; c < 4; ++c) {
            bf16x8 b = *(const bf16x8*)(Wmsg + (size_t)(wave * 64 + c * 16 + lr) * 384 + k0 + lk * 8);
            acc1[0][c] = MFMA16(a0, b, acc1[0][c]);
            acc1[1][c] = MFMA16(a1, b, acc1[1][c]);
            acc1[2][c] = MFMA16(a2, b, acc1[2][c]);
            acc1[3][c] = MFMA16(a3, b, acc1[3][c]);
        }
    }
    __syncthreads();    // all waves done reading xs[*][128..383] before overlay write

    // ---- GEMM_hn: hn = hv @ Whn^T (cols [0,128), disjoint from overlay) ----
    f32x4 acchn[4][2] = {};
    #pragma unroll
    for (int k0 = 0; k0 < 128; k0 += 32) {
        bf16x8 a0 = *(const bf16x8*)&xs[lr][k0 + lk * 8];
        bf16x8 a1 = *(const bf16x8*)&xs[16 + lr][k0 + lk * 8];
        bf16x8 a2 = *(const bf16x8*)&xs[32 + lr][k0 + lk * 8];
        bf16x8 a3 = *(const bf16x8*)&xs[48 + lr][k0 + lk * 8];
        #pragma unroll
        for (int j = 0; j < 2; ++j) {
            int o = wave * 32 + j * 16 + lr;
            bf16x8 b = *(const bf16x8*)(Whn + (size_t)o * 128 + k0 + lk * 8);
            acchn[0][j] = MFMA16(a0, b, acchn[0][j]);
            acchn[1][j] = MFMA16(a1, b, acchn[1][j]);
            acchn[2][j] = MFMA16(a2, b, acchn[2][j]);
            acchn[3][j] = MFMA16(a3, b, acchn[3][j]);
        }
    }

    // ---- write a (+bias) into xs[*][128 + n] ----
    #pragma unroll
    for (int mf = 0; mf < 4; ++mf) {
        #pragma unroll
        for (int c = 0; c < 4; ++c) {
            int n = wave * 64 + c * 16 + lr;
            float bias = bmsg[n];
            #pragma unroll
            for (int r = 0; r < 4; ++r) {
                int m = mf * 16 + lk * 4 + r;
                xs[m][128 + n] = (__bf16)(acc1[mf][c][r] + bias);
            }
        }
    }
    __syncthreads();

    // ---- GEMM_rz: rz = [hv|a] @ Wrz^T over K=384 ----
    f32x4 accrz[4][4] = {};
    #pragma unroll 2
    for (int k0 = 0; k0 < 384; k0 += 32) {
        bf16x8 a0 = *(const bf16x8*)&xs[lr][k0 + lk * 8];
        bf16x8 a1 = *(const bf16x8*)&xs[16 + lr][k0 + lk * 8];
        bf16x8 a2 = *(const bf16x8*)&xs[32 + lr][k0 + lk * 8];
        bf16x8 a3 = *(const bf16x8*)&xs[48 + lr][k0 + lk * 8];
        #pragma unroll
        for (int q = 0; q < 4; ++q) {
            int o = (q >> 1) * 128 + wave * 32 + (q & 1) * 16 + lr;
            bf16x8 b = *(const bf16x8*)(Wrz + (size_t)o * 384 + k0 + lk * 8);
            accrz[0][q] = MFMA16(a0, b, accrz[0][q]);
            accrz[1][q] = MFMA16(a1, b, accrz[1][q]);
            accrz[2][q] = MFMA16(a2, b, accrz[2][q]);
            accrz[3][q] = MFMA16(a3, b, accrz[3][q]);
        }
    }

    // ---- GEMM_in: in = a @ Win^T over K=256 ----
    f32x4 accin[4][2] = {};
    #pragma unroll 2
    for (int k0 = 0; k0 < 256; k0 += 32) {
        bf16x8 a0 = *(const bf16x8*)&xs[lr][128 + k0 + lk * 8];
        bf16x8 a1 = *(const bf16x8*)&xs[16 + lr][128 + k0 + lk * 8];
        bf16x8 a2 = *(const bf16x8*)&xs[32 + lr][128 + k0 + lk * 8];
        bf16x8 a3 = *(const bf16x8*)&xs[48 + lr][128 + k0 + lk * 8];
        #pragma unroll
        for (int j = 0; j < 2; ++j) {
            int o = wave * 32 + j * 16 + lr;
            bf16x8 b = *(const bf16x8*)(Win + (size_t)o * 256 + k0 + lk * 8);
            accin[0][j] = MFMA16(a0, b, accin[0][j]);
            accin[1][j] = MFMA16(a1, b, accin[1][j]);
            accin[2][j] = MFMA16(a2, b, accin[2][j]);
            accin[3][j] = MFMA16(a3, b, accin[3][j]);
        }
    }

    // ---- GRU epilogue ----
    #pragma unroll
    for (int mf = 0; mf < 4; ++mf) {
        #pragma unroll
        for (int j = 0; j < 2; ++j) {
            int hcol = wave * 32 + j * 16 + lr;
            float brz_r = bih[hcol]       + bhh[hcol];
            float brz_z = bih[128 + hcol] + bhh[128 + hcol];
            float b_in  = bih[256 + hcol];
            float b_hn  = bhh[256 + hcol];
            #pragma unroll
            for (int r = 0; r < 4; ++r) {
                int m = mf * 16 + lk * 4 + r;
                int node = m0 + m;
                if (node < N) {
                    float rg = 1.f / (1.f + __expf(-(accrz[mf][0 + j][r] + brz_r)));
                    float zg = 1.f / (1.f + __expf(-(accrz[mf][2 + j][r] + brz_z)));
                    float ng = tanhf(accin[mf][j][r] + b_in + rg * (acchn[mf][j][r] + b_hn));
                    float hold = hv_hold[(size_t)node * 128 + hcol];
                    float hnew = (1.f - zg) * ng + zg * hold;
                    hv_out[(size_t)node * 128 + hcol] = hnew;
                    if (WRITE_BF) hv_bf[(size_t)node * 128 + hcol] = (__bf16)hnew;
                }
            }
        }
    }
}

extern "C" void kernel_launch(void* const* d_in, const int* in_sizes, int n_in,
                              void* d_out, int out_size, void* d_ws, size_t ws_size,
                              hipStream_t stream)
{
    const float* hv   = (const float*)d_in[0];
    const float* he   = (const float*)d_in[1];
    const int*   src  = (const int*)d_in[2];
    const int*   dst  = (const int*)d_in[3];
    const float* Wmsg = (const float*)d_in[4];
    const float* bmsg = (const float*)d_in[5];
    const float* Wih  = (const float*)d_in[6];
    const float* Whh  = (const float*)d_in[7];
    const float* bih  = (const float*)d_in[8];
    const float* bhh  = (const float*)d_in[9];

    const int H = 128;
    const int N = in_sizes[0] / H;
    const int E = in_sizes[2];

    // ---- workspace layout ----
    char* w = (char*)d_ws;
    __bf16* he_mean   = (__bf16*)w;  w += (size_t)N * H * 2;
    __bf16* hsrc_mean = (__bf16*)w;  w += (size_t)N * H * 2;
    __bf16* hv_bf     = (__bf16*)w;  w += (size_t)N * H * 2;
    int* degi    = (int*)w;  w += (size_t)N * 4;
    int* counter = (int*)w;  w += 4;
    int* off     = (int*)w;  w += (size_t)N * 4;
    int* cnt     = (int*)w;  w += (size_t)N * 4;
    w = (char*)(((uintptr_t)w + 15) & ~(uintptr_t)15);
    int2* pairs  = (int2*)w; w += (size_t)E * 8;
    __bf16* wmsg_bf = (__bf16*)w;                       // [2][256][384]
    __bf16* wrz_bf  = wmsg_bf + 2 * 256 * 384;          // [2][256][384]
    __bf16* win_bf  = wrz_bf  + 2 * 256 * 384;          // [2][128][256]
    __bf16* whn_bf  = win_bf  + 2 * 128 * 256;          // [2][128][128]

    hipMemsetAsync(degi, 0, ((size_t)N + 1) * 4, stream);   // degi + counter

    const int prepack_total = 2*256*384 + 2*256*384 + 2*128*256 + 2*128*128;
    const int hv8    = N * H / 8;
    const int nb_pre = (prepack_total + 255) / 256;
    const int nb_hv  = (hv8 + 255) / 256;
    const int nb_deg = (E + 255) / 256;
    k_setup<<<nb_pre + nb_hv + nb_deg, 256, 0, stream>>>(
        Wmsg, Wih, Whh, hv, dst,
        wmsg_bf, wrz_bf, win_bf, whn_bf, hv_bf, degi,
        nb_pre, nb_hv, hv8, E);

    k_alloc<<<(N + 255) / 256, 256, 0, stream>>>(degi, off, cnt, counter, N);
    k_bucket<<<(E + 255) / 256, 256, 0, stream>>>(src, dst, off, cnt, pairs, E);

    float* out = (float*)d_out;
    const int nb_f = (N + 63) / 64;

    // round 1
    k_gather_both<<<(N + 3) / 4, 256, 0, stream>>>(hv_bf, he, pairs, off, degi,
                                                   hsrc_mean, he_mean, N);
    k_fused_round<true><<<nb_f, 256, 0, stream>>>(
        hv, hv_bf, hsrc_mean, he_mean,
        wmsg_bf, bmsg, wrz_bf, win_bf, whn_bf, bih, bhh, out, N);

    // round 2 (hv_bf updated by round 1's epilogue; safe across dispatch boundary)
    k_gather_hv<<<(N + 3) / 4, 256, 0, stream>>>(hv_bf, pairs, off, degi, hsrc_mean, N);
    k_fused_round<false><<<nb_f, 256, 0, stream>>>(
        out, hv_bf, hsrc_mean, he_mean,
        wmsg_bf + (size_t)256 * 384, bmsg + 256,
        wrz_bf + (size_t)256 * 384, win_bf + (size_t)128 * 256, whn_bf + (size_t)128 * 128,
        bih + 384, bhh + 384, out, N);
}

// Round 10
// 453.296 us; speedup vs baseline: 1.2012x; 1.0209x over previous
//
#include <hip/hip_runtime.h>
#include <hip/hip_bf16.h>

typedef __bf16 bf16x8 __attribute__((ext_vector_type(8)));
typedef __bf16 bf16x2 __attribute__((ext_vector_type(2)));
typedef float  f32x4  __attribute__((ext_vector_type(4)));

#define MFMA16(a,b,c) __builtin_amdgcn_mfma_f32_16x16x32_bf16((a),(b),(c),0,0,0)

// ---------------- setup: weight prepack + hv->bf16 + degree count, one dispatch -------
__global__ void k_setup(const float* __restrict__ wmsg, const float* __restrict__ wih,
                        const float* __restrict__ whh, const float* __restrict__ hv,
                        const int* __restrict__ dst,
                        __bf16* __restrict__ o_msg, __bf16* __restrict__ o_rz,
                        __bf16* __restrict__ o_in, __bf16* __restrict__ o_hn,
                        __bf16* __restrict__ hv_bf, int* __restrict__ degi,
                        int nb_pre, int nb_hv, int hv8, int E) {
    const int C1 = 2 * 256 * 384;
    const int C2 = C1 + 2 * 256 * 384;
    const int C3 = C2 + 2 * 128 * 256;
    const int C4 = C3 + 2 * 128 * 128;
    int b = blockIdx.x;
    if (b < nb_pre) {
        int i = b * 256 + threadIdx.x;
        if (i >= C4) return;
        if (i < C1) {
            o_msg[i] = (__bf16)wmsg[i];
        } else if (i < C2) {
            int p = i - C1;
            int t = p / 98304, rem = p % 98304;
            int o = rem / 384, c = rem % 384;
            float v = (c < 128) ? whh[t * 49152 + o * 128 + c]
                                : wih[t * 98304 + o * 256 + (c - 128)];
            o_rz[p] = (__bf16)v;
        } else if (i < C3) {
            int p = i - C2;
            int t = p / 32768, rem = p % 32768;
            int j = rem / 256, k = rem % 256;
            o_in[p] = (__bf16)wih[t * 98304 + (256 + j) * 256 + k];
        } else {
            int p = i - C3;
            int t = p / 16384, rem = p % 16384;
            int j = rem / 128, k = rem % 128;
            o_hn[p] = (__bf16)whh[t * 49152 + (256 + j) * 128 + k];
        }
    } else if (b < nb_pre + nb_hv) {
        int i = (b - nb_pre) * 256 + threadIdx.x;
        if (i >= hv8) return;
        const float4* p = (const float4*)(hv + (size_t)i * 8);
        float4 a = p[0], c = p[1];
        bf16x8 o;
        o[0] = (__bf16)a.x; o[1] = (__bf16)a.y; o[2] = (__bf16)a.z; o[3] = (__bf16)a.w;
        o[4] = (__bf16)c.x; o[5] = (__bf16)c.y; o[6] = (__bf16)c.z; o[7] = (__bf16)c.w;
        *(bf16x8*)(hv_bf + (size_t)i * 8) = o;
    } else {
        int e = (b - nb_pre - nb_hv) * 256 + threadIdx.x;
        if (e < E) atomicAdd(&degi[dst[e]], 1);
    }
}

// ---------------- CSR build ----------------
__global__ void k_alloc(const int* __restrict__ degi, int* __restrict__ off,
                        int* __restrict__ cnt, int* __restrict__ counter, int N) {
    int i = blockIdx.x * 256 + threadIdx.x;
    int lane = (int)threadIdx.x & 63;
    int v = (i < N) ? degi[i] : 0;
    int incl = v;
    #pragma unroll
    for (int d = 1; d < 64; d <<= 1) {
        int t = __shfl_up(incl, d, 64);
        if (lane >= d) incl += t;
    }
    int base = 0;
    if (lane == 63) base = atomicAdd(counter, incl);
    base = __shfl(base, 63, 64);
    if (i < N) { off[i] = base + incl - v; cnt[i] = 0; }
}

__global__ void k_bucket(const int* __restrict__ src, const int* __restrict__ dst,
                         const int* __restrict__ off, int* __restrict__ cnt,
                         int2* __restrict__ pairs, int E) {
    int e = blockIdx.x * 256 + threadIdx.x;
    if (e < E) {
        int d = dst[e];
        int p = off[d] + atomicAdd(&cnt[d], 1);
        pairs[p] = make_int2(src[e], e);
    }
}

// ---------------- round-1 gather: mean(hv_bf[src]) and mean(he[eid]) ----------------
// One wave per node; 4 lane-groups of 16 handle interleaved edges; lane reads 16B chunk.
// One VMEM instruction covers 4 edge-rows (1KB). Cross-group shfl_xor reduce at end.
__global__ void k_gather_both(const __bf16* __restrict__ hv_bf, const float* __restrict__ he,
                              const int2* __restrict__ pairs,
                              const int* __restrict__ off, const int* __restrict__ degi,
                              __bf16* __restrict__ hsrc_mean, __bf16* __restrict__ he_mean,
                              int N) {
    int node = blockIdx.x * 4 + ((int)threadIdx.x >> 6);
    if (node >= N) return;
    int lane = (int)threadIdx.x & 63;
    int grp  = lane >> 4;          // edge group 0..3
    int c8   = (lane & 15) * 8;    // col block [c8, c8+8)
    int beg = off[node], deg = degi[node];
    int end = beg + deg;
    float ah[8] = {0.f,0.f,0.f,0.f,0.f,0.f,0.f,0.f};
    float ae[8] = {0.f,0.f,0.f,0.f,0.f,0.f,0.f,0.f};
    for (int p = beg + grp; p < end; p += 4) {
        int2 a = pairs[p];
        bf16x8 v  = *(const bf16x8*)(hv_bf + (size_t)a.x * 128 + c8);
        float4 w0 = *(const float4*)(he + (size_t)a.y * 128 + c8);
        float4 w1 = *(const float4*)(he + (size_t)a.y * 128 + c8 + 4);
        #pragma unroll
        for (int j = 0; j < 8; ++j) ah[j] += (float)v[j];
        ae[0] += w0.x; ae[1] += w0.y; ae[2] += w0.z; ae[3] += w0.w;
        ae[4] += w1.x; ae[5] += w1.y; ae[6] += w1.z; ae[7] += w1.w;
    }
    #pragma unroll
    for (int j = 0; j < 8; ++j) {
        ah[j] += __shfl_xor(ah[j], 16, 64);
        ah[j] += __shfl_xor(ah[j], 32, 64);
        ae[j] += __shfl_xor(ae[j], 16, 64);
        ae[j] += __shfl_xor(ae[j], 32, 64);
    }
    if (lane < 16) {
        float s = 1.0f / fmaxf((float)deg, 1.0f);
        bf16x8 oh, oe;
        #pragma unroll
        for (int j = 0; j < 8; ++j) {
            oh[j] = (__bf16)(ah[j] * s);
            oe[j] = (__bf16)(ae[j] * s);
        }
        *(bf16x8*)(hsrc_mean + (size_t)node * 128 + c8) = oh;
        *(bf16x8*)(he_mean   + (size_t)node * 128 + c8) = oe;
    }
}

// ---------------- round-2 gather: mean(hv_bf[src]) only ----------------
__global__ void k_gather_hv(const __bf16* __restrict__ hv_bf, const int2* __restrict__ pairs,
                            const int* __restrict__ off, const int* __restrict__ degi,
                            __bf16* __restrict__ hsrc_mean, int N) {
    int node = blockIdx.x * 4 + ((int)threadIdx.x >> 6);
    if (node >= N) return;
    int lane = (int)threadIdx.x & 63;
    int grp  = lane >> 4;
    int c8   = (lane & 15) * 8;
    int beg = off[node], deg = degi[node];
    int end = beg + deg;
    float ah[8] = {0.f,0.f,0.f,0.f,0.f,0.f,0.f,0.f};
    for (int p = beg + grp; p < end; p += 4) {
        int2 a = pairs[p];
        bf16x8 v = *(const bf16x8*)(hv_bf + (size_t)a.x * 128 + c8);
        #pragma unroll
        for (int j = 0; j < 8; ++j) ah[j] += (float)v[j];
    }
    #pragma unroll
    for (int j = 0; j < 8; ++j) {
        ah[j] += __shfl_xor(ah[j], 16, 64);
        ah[j] += __shfl_xor(ah[j], 32, 64);
    }
    if (lane < 16) {
        float s = 1.0f / fmaxf((float)deg, 1.0f);
        bf16x8 o;
        #pragma unroll
        for (int j = 0; j < 8; ++j) o[j] = (__bf16)(ah[j] * s);
        *(bf16x8*)(hsrc_mean + (size_t)node * 128 + c8) = o;
    }
}

// ---------------- fused round, BM=64 (4 waves / 256 thr) ----------------
template<bool WRITE_BF>
__launch_bounds__(256, 2)
__global__ void k_fused_round(
    const float* __restrict__ hv_hold,
    __bf16* __restrict__ hv_bf,
    const __bf16* __restrict__ hsrc_mean,
    const __bf16* __restrict__ he_mean,
    const __bf16* __restrict__ Wmsg,       // [256,384]
    const float* __restrict__ bmsg,        // [256]
    const __bf16* __restrict__ Wrz,        // [256,384]
    const __bf16* __restrict__ Win,        // [128,256]
    const __bf16* __restrict__ Whn,        // [128,128]
    const float* __restrict__ bih,         // [384]
    const float* __restrict__ bhh,         // [384]
    float* __restrict__ hv_out, int N)
{
    __shared__ __bf16 xs[64][392];   // 384 + 8 pad; [128,384) reused for 'a' after GEMM1

    const int tid = threadIdx.x;
    const int m0  = blockIdx.x * 64;

    for (int idx = tid; idx < 64 * 48; idx += 256) {
        int row = idx / 48;
        int c   = idx - row * 48;
        int part = c >> 4;
        int c8   = (c & 15) * 8;
        int node = m0 + row;
        const __bf16* base = (part == 0) ? hv_bf : ((part == 1) ? hsrc_mean : he_mean);
        bf16x8 v = {};
        if (node < N) v = *(const bf16x8*)(base + (size_t)node * 128 + c8);
        *(bf16x8*)&xs[row][part * 128 + c8] = v;
    }
    __syncthreads();

    const int wave = tid >> 6;
    const int lane = tid & 63;
    const int lr = lane & 15;
    const int lk = lane >> 4;

    // ---- GEMM1: a = x @ Wmsg^T ----
    f32x4 acc1[4][4] = {};
    #pragma unroll 2
    for (int k0 = 0; k0 < 384; k0 += 32) {
        bf16x8 a0 = *(const bf16x8*)&xs[lr][k0 + lk * 8];
        bf16x8 a1 = *(const bf16x8*)&xs[16 + lr][k0 + lk * 8];
        bf16x8 a2 = *(const bf16x8*)&xs[32 + lr][k0 + lk * 8];
        bf16x8 a3 = *(const bf16x8*)&xs[48 + lr][k0 + lk * 8];
        #pragma unroll
        for (int c = 0; c < 4; ++c) {
            bf16x8 b = *(const bf16x8*)(Wmsg + (size_t)(wave * 64 + c * 16 + lr) * 384 + k0 + lk * 8);
            acc1[0][c] = MFMA16(a0, b, acc1[0][c]);
            acc1[1][c] = MFMA16(a1, b, acc1[1][c]);
            acc1[2][c] = MFMA16(a2, b, acc1[2][c]);
            acc1[3][c] = MFMA16(a3, b, acc1[3][c]);
        }
    }
    __syncthreads();

    // ---- GEMM_hn: hn = hv @ Whn^T ----
    f32x4 acchn[4][2] = {};
    #pragma unroll
    for (int k0 = 0; k0 < 128; k0 += 32) {
        bf16x8 a0 = *(const bf16x8*)&xs[lr][k0 + lk * 8];
        bf16x8 a1 = *(const bf16x8*)&xs[16 + lr][k0 + lk * 8];
        bf16x8 a2 = *(const bf16x8*)&xs[32 + lr][k0 + lk * 8];
        bf16x8 a3 = *(const bf16x8*)&xs[48 + lr][k0 + lk * 8];
        #pragma unroll
        for (int j = 0; j < 2; ++j) {
            int o = wave * 32 + j * 16 + lr;
            bf16x8 b = *(const bf16x8*)(Whn + (size_t)o * 128 + k0 + lk * 8);
            acchn[0][j] = MFMA16(a0, b, acchn[0][j]);
            acchn[1][j] = MFMA16(a1, b, acchn[1][j]);
            acchn[2][j] = MFMA16(a2, b, acchn[2][j]);
            acchn[3][j] = MFMA16(a3, b, acchn[3][j]);
        }
    }

    // ---- write a (+bias) into xs[*][128 + n] ----
    #pragma unroll
    for (int mf = 0; mf < 4; ++mf) {
        #pragma unroll
        for (int c = 0; c < 4; ++c) {
            int n = wave * 64 + c * 16 + lr;
            float bias = bmsg[n];
            #pragma unroll
            for (int r = 0; r < 4; ++r) {
                int m = mf * 16 + lk * 4 + r;
                xs[m][128 + n] = (__bf16)(acc1[mf][c][r] + bias);
            }
        }
    }
    __syncthreads();

    // ---- GEMM_rz: rz = [hv|a] @ Wrz^T over K=384 ----
    f32x4 accrz[4][4] = {};
    #pragma unroll 2
    for (int k0 = 0; k0 < 384; k0 += 32) {
        bf16x8 a0 = *(const bf16x8*)&xs[lr][k0 + lk * 8];
        bf16x8 a1 = *(const bf16x8*)&xs[16 + lr][k0 + lk * 8];
        bf16x8 a2 = *(const bf16x8*)&xs[32 + lr][k0 + lk * 8];
        bf16x8 a3 = *(const bf16x8*)&xs[48 + lr][k0 + lk * 8];
        #pragma unroll
        for (int q = 0; q < 4; ++q) {
            int o = (q >> 1) * 128 + wave * 32 + (q & 1) * 16 + lr;
            bf16x8 b = *(const bf16x8*)(Wrz + (size_t)o * 384 + k0 + lk * 8);
            accrz[0][q] = MFMA16(a0, b, accrz[0][q]);
            accrz[1][q] = MFMA16(a1, b, accrz[1][q]);
            accrz[2][q] = MFMA16(a2, b, accrz[2][q]);
            accrz[3][q] = MFMA16(a3, b, accrz[3][q]);
        }
    }

    // ---- GEMM_in: in = a @ Win^T over K=256 ----
    f32x4 accin[4][2] = {};
    #pragma unroll 2
    for (int k0 = 0; k0 < 256; k0 += 32) {
        bf16x8 a0 = *(const bf16x8*)&xs[lr][128 + k0 + lk * 8];
        bf16x8 a1 = *(const bf16x8*)&xs[16 + lr][128 + k0 + lk * 8];
        bf16x8 a2 = *(const bf16x8*)&xs[32 + lr][128 + k0 + lk * 8];
        bf16x8 a3 = *(const bf16x8*)&xs[48 + lr][128 + k0 + lk * 8];
        #pragma unroll
        for (int j = 0; j < 2; ++j) {
            int o = wave * 32 + j * 16 + lr;
            bf16x8 b = *(const bf16x8*)(Win + (size_t)o * 256 + k0 + lk * 8);
            accin[0][j] = MFMA16(a0, b, accin[0][j]);
            accin[1][j] = MFMA16(a1, b, accin[1][j]);
            accin[2][j] = MFMA16(a2, b, accin[2][j]);
            accin[3][j] = MFMA16(a3, b, accin[3][j]);
        }
    }

    // ---- GRU epilogue ----
    #pragma unroll
    for (int mf = 0; mf < 4; ++mf) {
        #pragma unroll
        for (int j = 0; j < 2; ++j) {
            int hcol = wave * 32 + j * 16 + lr;
            float brz_r = bih[hcol]       + bhh[hcol];
            float brz_z = bih[128 + hcol] + bhh[128 + hcol];
            float b_in  = bih[256 + hcol];
            float b_hn  = bhh[256 + hcol];
            #pragma unroll
            for (int r = 0; r < 4; ++r) {
                int m = mf * 16 + lk * 4 + r;
                int node = m0 + m;
                if (node < N) {
                    float rg = 1.f / (1.f + __expf(-(accrz[mf][0 + j][r] + brz_r)));
                    float zg = 1.f / (1.f + __expf(-(accrz[mf][2 + j][r] + brz_z)));
                    float ng = tanhf(accin[mf][j][r] + b_in + rg * (acchn[mf][j][r] + b_hn));
                    float hold = hv_hold[(size_t)node * 128 + hcol];
                    float hnew = (1.f - zg) * ng + zg * hold;
                    hv_out[(size_t)node * 128 + hcol] = hnew;
                    if (WRITE_BF) hv_bf[(size_t)node * 128 + hcol] = (__bf16)hnew;
                }
            }
        }
    }
}

extern "C" void kernel_launch(void* const* d_in, const int* in_sizes, int n_in,
                              void* d_out, int out_size, void* d_ws, size_t ws_size,
                              hipStream_t stream)
{
    const float* hv   = (const float*)d_in[0];
    const float* he   = (const float*)d_in[1];
    const int*   src  = (const int*)d_in[2];
    const int*   dst  = (const int*)d_in[3];
    const float* Wmsg = (const float*)d_in[4];
    const float* bmsg = (const float*)d_in[5];
    const float* Wih  = (const float*)d_in[6];
    const float* Whh  = (const float*)d_in[7];
    const float* bih  = (const float*)d_in[8];
    const float* bhh  = (const float*)d_in[9];

    const int H = 128;
    const int N = in_sizes[0] / H;
    const int E = in_sizes[2];

    // ---- workspace layout ----
    char* w = (char*)d_ws;
    __bf16* he_mean   = (__bf16*)w;  w += (size_t)N * H * 2;
    __bf16* hsrc_mean = (__bf16*)w;  w += (size_t)N * H * 2;
    __bf16* hv_bf     = (__bf16*)w;  w += (size_t)N * H * 2;
    int* degi    = (int*)w;  w += (size_t)N * 4;
    int* counter = (int*)w;  w += 4;
    int* off     = (int*)w;  w += (size_t)N * 4;
    int* cnt     = (int*)w;  w += (size_t)N * 4;
    w = (char*)(((uintptr_t)w + 15) & ~(uintptr_t)15);
    int2* pairs  = (int2*)w; w += (size_t)E * 8;
    __bf16* wmsg_bf = (__bf16*)w;                       // [2][256][384]
    __bf16* wrz_bf  = wmsg_bf + 2 * 256 * 384;          // [2][256][384]
    __bf16* win_bf  = wrz_bf  + 2 * 256 * 384;          // [2][128][256]
    __bf16* whn_bf  = win_bf  + 2 * 128 * 256;          // [2][128][128]

    hipMemsetAsync(degi, 0, ((size_t)N + 1) * 4, stream);   // degi + counter

    const int prepack_total = 2*256*384 + 2*256*384 + 2*128*256 + 2*128*128;
    const int hv8    = N * H / 8;
    const int nb_pre = (prepack_total + 255) / 256;
    const int nb_hv  = (hv8 + 255) / 256;
    const int nb_deg = (E + 255) / 256;
    k_setup<<<nb_pre + nb_hv + nb_deg, 256, 0, stream>>>(
        Wmsg, Wih, Whh, hv, dst,
        wmsg_bf, wrz_bf, win_bf, whn_bf, hv_bf, degi,
        nb_pre, nb_hv, hv8, E);

    k_alloc<<<(N + 255) / 256, 256, 0, stream>>>(degi, off, cnt, counter, N);
    k_bucket<<<(E + 255) / 256, 256, 0, stream>>>(src, dst, off, cnt, pairs, E);

    float* out = (float*)d_out;
    const int nb_f = (N + 63) / 64;

    // round 1
    k_gather_both<<<(N + 3) / 4, 256, 0, stream>>>(hv_bf, he, pairs, off, degi,
                                                   hsrc_mean, he_mean, N);
    k_fused_round<true><<<nb_f, 256, 0, stream>>>(
        hv, hv_bf, hsrc_mean, he_mean,
        wmsg_bf, bmsg, wrz_bf, win_bf, whn_bf, bih, bhh, out, N);

    // round 2 (hv_bf updated by round 1's epilogue; ordering via dispatch boundary)
    k_gather_hv<<<(N + 3) / 4, 256, 0, stream>>>(hv_bf, pairs, off, degi, hsrc_mean, N);
    k_fused_round<false><<<nb_f, 256, 0, stream>>>(
        out, hv_bf, hsrc_mean, he_mean,
        wmsg_bf + (size_t)256 * 384, bmsg + 256,
        wrz_bf + (size_t)256 * 384, win_bf + (size_t)128 * 256, whn_bf + (size_t)128 * 128,
        bih + 384, bhh + 384, out, N);
}

// Round 11
// 437.741 us; speedup vs baseline: 1.2439x; 1.0355x over previous
//
#include <hip/hip_runtime.h>
#include <hip/hip_bf16.h>

typedef __bf16 bf16x8 __attribute__((ext_vector_type(8)));
typedef __bf16 bf16x2 __attribute__((ext_vector_type(2)));
typedef float  f32x4  __attribute__((ext_vector_type(4)));

#define MFMA16(a,b,c) __builtin_amdgcn_mfma_f32_16x16x32_bf16((a),(b),(c),0,0,0)

// ---------------- setup: weight prepack + hv->bf16 + degree count, one dispatch -------
__global__ void k_setup(const float* __restrict__ wmsg, const float* __restrict__ wih,
                        const float* __restrict__ whh, const float* __restrict__ hv,
                        const int* __restrict__ dst,
                        __bf16* __restrict__ o_msg, __bf16* __restrict__ o_rz,
                        __bf16* __restrict__ o_in, __bf16* __restrict__ o_hn,
                        __bf16* __restrict__ hv_bf, int* __restrict__ degi,
                        int nb_pre, int nb_hv, int hv8, int E) {
    const int C1 = 2 * 256 * 384;
    const int C2 = C1 + 2 * 256 * 384;
    const int C3 = C2 + 2 * 128 * 256;
    const int C4 = C3 + 2 * 128 * 128;
    int b = blockIdx.x;
    if (b < nb_pre) {
        int i = b * 256 + threadIdx.x;
        if (i >= C4) return;
        if (i < C1) {
            o_msg[i] = (__bf16)wmsg[i];
        } else if (i < C2) {
            int p = i - C1;
            int t = p / 98304, rem = p % 98304;
            int o = rem / 384, c = rem % 384;
            float v = (c < 128) ? whh[t * 49152 + o * 128 + c]
                                : wih[t * 98304 + o * 256 + (c - 128)];
            o_rz[p] = (__bf16)v;
        } else if (i < C3) {
            int p = i - C2;
            int t = p / 32768, rem = p % 32768;
            int j = rem / 256, k = rem % 256;
            o_in[p] = (__bf16)wih[t * 98304 + (256 + j) * 256 + k];
        } else {
            int p = i - C3;
            int t = p / 16384, rem = p % 16384;
            int j = rem / 128, k = rem % 128;
            o_hn[p] = (__bf16)whh[t * 49152 + (256 + j) * 128 + k];
        }
    } else if (b < nb_pre + nb_hv) {
        int i = (b - nb_pre) * 256 + threadIdx.x;
        if (i >= hv8) return;
        const float4* p = (const float4*)(hv + (size_t)i * 8);
        float4 a = p[0], c = p[1];
        bf16x8 o;
        o[0] = (__bf16)a.x; o[1] = (__bf16)a.y; o[2] = (__bf16)a.z; o[3] = (__bf16)a.w;
        o[4] = (__bf16)c.x; o[5] = (__bf16)c.y; o[6] = (__bf16)c.z; o[7] = (__bf16)c.w;
        *(bf16x8*)(hv_bf + (size_t)i * 8) = o;
    } else {
        int e = (b - nb_pre - nb_hv) * 256 + threadIdx.x;
        if (e < E) atomicAdd(&degi[dst[e]], 1);
    }
}

// ---------------- CSR build ----------------
__global__ void k_alloc(const int* __restrict__ degi, int* __restrict__ off,
                        int* __restrict__ cnt, int* __restrict__ counter, int N) {
    int i = blockIdx.x * 256 + threadIdx.x;
    int lane = (int)threadIdx.x & 63;
    int v = (i < N) ? degi[i] : 0;
    int incl = v;
    #pragma unroll
    for (int d = 1; d < 64; d <<= 1) {
        int t = __shfl_up(incl, d, 64);
        if (lane >= d) incl += t;
    }
    int base = 0;
    if (lane == 63) base = atomicAdd(counter, incl);
    base = __shfl(base, 63, 64);
    if (i < N) { off[i] = base + incl - v; cnt[i] = 0; }
}

__global__ void k_bucket(const int* __restrict__ src, const int* __restrict__ dst,
                         const int* __restrict__ off, int* __restrict__ cnt,
                         int2* __restrict__ pairs, int E) {
    int e = blockIdx.x * 256 + threadIdx.x;
    if (e < E) {
        int d = dst[e];
        int p = off[d] + atomicAdd(&cnt[d], 1);
        pairs[p] = make_int2(src[e], e);
    }
}

// ---------------- round-1 gather: mean(hv_bf[src]) and mean(he[eid]) ----------------
// One wave per node; 4 lane-groups of 16 handle interleaved edges; lane reads 16B chunk.
// Unroll-2 (edges p, p+4 in flight) with independent accumulators; he loads nontemporal
// (read-once 410MB stream must not evict the reused hv_bf/pairs from L2).
__global__ void k_gather_both(const __bf16* __restrict__ hv_bf, const float* __restrict__ he,
                              const int2* __restrict__ pairs,
                              const int* __restrict__ off, const int* __restrict__ degi,
                              __bf16* __restrict__ hsrc_mean, __bf16* __restrict__ he_mean,
                              int N) {
    int node = blockIdx.x * 4 + ((int)threadIdx.x >> 6);
    if (node >= N) return;
    int lane = (int)threadIdx.x & 63;
    int grp  = lane >> 4;          // edge group 0..3
    int c8   = (lane & 15) * 8;    // col block [c8, c8+8)
    int beg = off[node], deg = degi[node];
    int end = beg + deg;
    float ah[8] = {0.f,0.f,0.f,0.f,0.f,0.f,0.f,0.f};
    float bh[8] = {0.f,0.f,0.f,0.f,0.f,0.f,0.f,0.f};
    float ae[8] = {0.f,0.f,0.f,0.f,0.f,0.f,0.f,0.f};
    float be[8] = {0.f,0.f,0.f,0.f,0.f,0.f,0.f,0.f};
    int p = beg + grp;
    for (; p + 4 < end; p += 8) {
        int2 a = pairs[p];
        int2 b = pairs[p + 4];
        bf16x8 va = *(const bf16x8*)(hv_bf + (size_t)a.x * 128 + c8);
        bf16x8 vb = *(const bf16x8*)(hv_bf + (size_t)b.x * 128 + c8);
        f32x4 wa0 = __builtin_nontemporal_load((const f32x4*)(he + (size_t)a.y * 128 + c8));
        f32x4 wa1 = __builtin_nontemporal_load((const f32x4*)(he + (size_t)a.y * 128 + c8 + 4));
        f32x4 wb0 = __builtin_nontemporal_load((const f32x4*)(he + (size_t)b.y * 128 + c8));
        f32x4 wb1 = __builtin_nontemporal_load((const f32x4*)(he + (size_t)b.y * 128 + c8 + 4));
        #pragma unroll
        for (int j = 0; j < 8; ++j) { ah[j] += (float)va[j]; bh[j] += (float)vb[j]; }
        #pragma unroll
        for (int j = 0; j < 4; ++j) {
            ae[j]     += wa0[j]; ae[j + 4] += wa1[j];
            be[j]     += wb0[j]; be[j + 4] += wb1[j];
        }
    }
    if (p < end) {
        int2 a = pairs[p];
        bf16x8 va = *(const bf16x8*)(hv_bf + (size_t)a.x * 128 + c8);
        f32x4 wa0 = __builtin_nontemporal_load((const f32x4*)(he + (size_t)a.y * 128 + c8));
        f32x4 wa1 = __builtin_nontemporal_load((const f32x4*)(he + (size_t)a.y * 128 + c8 + 4));
        #pragma unroll
        for (int j = 0; j < 8; ++j) ah[j] += (float)va[j];
        #pragma unroll
        for (int j = 0; j < 4; ++j) { ae[j] += wa0[j]; ae[j + 4] += wa1[j]; }
    }
    #pragma unroll
    for (int j = 0; j < 8; ++j) {
        ah[j] += bh[j]; ae[j] += be[j];
        ah[j] += __shfl_xor(ah[j], 16, 64);
        ah[j] += __shfl_xor(ah[j], 32, 64);
        ae[j] += __shfl_xor(ae[j], 16, 64);
        ae[j] += __shfl_xor(ae[j], 32, 64);
    }
    if (lane < 16) {
        float s = 1.0f / fmaxf((float)deg, 1.0f);
        bf16x8 oh, oe;
        #pragma unroll
        for (int j = 0; j < 8; ++j) {
            oh[j] = (__bf16)(ah[j] * s);
            oe[j] = (__bf16)(ae[j] * s);
        }
        *(bf16x8*)(hsrc_mean + (size_t)node * 128 + c8) = oh;
        *(bf16x8*)(he_mean   + (size_t)node * 128 + c8) = oe;
    }
}

// ---------------- round-2 gather: mean(hv_bf[src]) only ----------------
__global__ void k_gather_hv(const __bf16* __restrict__ hv_bf, const int2* __restrict__ pairs,
                            const int* __restrict__ off, const int* __restrict__ degi,
                            __bf16* __restrict__ hsrc_mean, int N) {
    int node = blockIdx.x * 4 + ((int)threadIdx.x >> 6);
    if (node >= N) return;
    int lane = (int)threadIdx.x & 63;
    int grp  = lane >> 4;
    int c8   = (lane & 15) * 8;
    int beg = off[node], deg = degi[node];
    int end = beg + deg;
    float ah[8] = {0.f,0.f,0.f,0.f,0.f,0.f,0.f,0.f};
    float bh[8] = {0.f,0.f,0.f,0.f,0.f,0.f,0.f,0.f};
    int p = beg + grp;
    for (; p + 4 < end; p += 8) {
        int2 a = pairs[p];
        int2 b = pairs[p + 4];
        bf16x8 va = *(const bf16x8*)(hv_bf + (size_t)a.x * 128 + c8);
        bf16x8 vb = *(const bf16x8*)(hv_bf + (size_t)b.x * 128 + c8);
        #pragma unroll
        for (int j = 0; j < 8; ++j) { ah[j] += (float)va[j]; bh[j] += (float)vb[j]; }
    }
    if (p < end) {
        int2 a = pairs[p];
        bf16x8 va = *(const bf16x8*)(hv_bf + (size_t)a.x * 128 + c8);
        #pragma unroll
        for (int j = 0; j < 8; ++j) ah[j] += (float)va[j];
    }
    #pragma unroll
    for (int j = 0; j < 8; ++j) {
        ah[j] += bh[j];
        ah[j] += __shfl_xor(ah[j], 16, 64);
        ah[j] += __shfl_xor(ah[j], 32, 64);
    }
    if (lane < 16) {
        float s = 1.0f / fmaxf((float)deg, 1.0f);
        bf16x8 o;
        #pragma unroll
        for (int j = 0; j < 8; ++j) o[j] = (__bf16)(ah[j] * s);
        *(bf16x8*)(hsrc_mean + (size_t)node * 128 + c8) = o;
    }
}

// ---------------- fused round, BM=64 (4 waves / 256 thr) ----------------
template<bool WRITE_BF>
__launch_bounds__(256, 2)
__global__ void k_fused_round(
    const float* __restrict__ hv_hold,
    __bf16* __restrict__ hv_bf,
    const __bf16* __restrict__ hsrc_mean,
    const __bf16* __restrict__ he_mean,
    const __bf16* __restrict__ Wmsg,       // [256,384]
    const float* __restrict__ bmsg,        // [256]
    const __bf16* __restrict__ Wrz,        // [256,384]
    const __bf16* __restrict__ Win,        // [128,256]
    const __bf16* __restrict__ Whn,        // [128,128]
    const float* __restrict__ bih,         // [384]
    const float* __restrict__ bhh,         // [384]
    float* __restrict__ hv_out, int N)
{
    __shared__ __bf16 xs[64][392];   // 384 + 8 pad; [128,384) reused for 'a' after GEMM1

    const int tid = threadIdx.x;
    const int m0  = blockIdx.x * 64;

    for (int idx = tid; idx < 64 * 48; idx += 256) {
        int row = idx / 48;
        int c   = idx - row * 48;
        int part = c >> 4;
        int c8   = (c & 15) * 8;
        int node = m0 + row;
        const __bf16* base = (part == 0) ? hv_bf : ((part == 1) ? hsrc_mean : he_mean);
        bf16x8 v = {};
        if (node < N) v = *(const bf16x8*)(base + (size_t)node * 128 + c8);
        *(bf16x8*)&xs[row][part * 128 + c8] = v;
    }
    __syncthreads();

    const int wave = tid >> 6;
    const int lane = tid & 63;
    const int lr = lane & 15;
    const int lk = lane >> 4;

    // ---- GEMM1: a = x @ Wmsg^T ----
    f32x4 acc1[4][4] = {};
    #pragma unroll 2
    for (int k0 = 0; k0 < 384; k0 += 32) {
        bf16x8 a0 = *(const bf16x8*)&xs[lr][k0 + lk * 8];
        bf16x8 a1 = *(const bf16x8*)&xs[16 + lr][k0 + lk * 8];
        bf16x8 a2 = *(const bf16x8*)&xs[32 + lr][k0 + lk * 8];
        bf16x8 a3 = *(const bf16x8*)&xs[48 + lr][k0 + lk * 8];
        #pragma unroll
        for (int c = 0; c < 4; ++c) {
            bf16x8 b = *(const bf16x8*)(Wmsg + (size_t)(wave * 64 + c * 16 + lr) * 384 + k0 + lk * 8);
            acc1[0][c] = MFMA16(a0, b, acc1[0][c]);
            acc1[1][c] = MFMA16(a1, b, acc1[1][c]);
            acc1[2][c] = MFMA16(a2, b, acc1[2][c]);
            acc1[3][c] = MFMA16(a3, b, acc1[3][c]);
        }
    }
    __syncthreads();

    // ---- GEMM_hn: hn = hv @ Whn^T ----
    f32x4 acchn[4][2] = {};
    #pragma unroll
    for (int k0 = 0; k0 < 128; k0 += 32) {
        bf16x8 a0 = *(const bf16x8*)&xs[lr][k0 + lk * 8];
        bf16x8 a1 = *(const bf16x8*)&xs[16 + lr][k0 + lk * 8];
        bf16x8 a2 = *(const bf16x8*)&xs[32 + lr][k0 + lk * 8];
        bf16x8 a3 = *(const bf16x8*)&xs[48 + lr][k0 + lk * 8];
        #pragma unroll
        for (int j = 0; j < 2; ++j) {
            int o = wave * 32 + j * 16 + lr;
            bf16x8 b = *(const bf16x8*)(Whn + (size_t)o * 128 + k0 + lk * 8);
            acchn[0][j] = MFMA16(a0, b, acchn[0][j]);
            acchn[1][j] = MFMA16(a1, b, acchn[1][j]);
            acchn[2][j] = MFMA16(a2, b, acchn[2][j]);
            acchn[3][j] = MFMA16(a3, b, acchn[3][j]);
        }
    }

    // ---- write a (+bias) into xs[*][128 + n] ----
    #pragma unroll
    for (int mf = 0; mf < 4; ++mf) {
        #pragma unroll
        for (int c = 0; c < 4; ++c) {
            int n = wave * 64 + c * 16 + lr;
            float bias = bmsg[n];
            #pragma unroll
            for (int r = 0; r < 4; ++r) {
                int m = mf * 16 + lk * 4 + r;
                xs[m][128 + n] = (__bf16)(acc1[mf][c][r] + bias);
            }
        }
    }
    __syncthreads();

    // ---- GEMM_rz: rz = [hv|a] @ Wrz^T over K=384 ----
    f32x4 accrz[4][4] = {};
    #pragma unroll 2
    for (int k0 = 0; k0 < 384; k0 += 32) {
        bf16x8 a0 = *(const bf16x8*)&xs[lr][k0 + lk * 8];
        bf16x8 a1 = *(const bf16x8*)&xs[16 + lr][k0 + lk * 8];
        bf16x8 a2 = *(const bf16x8*)&xs[32 + lr][k0 + lk * 8];
        bf16x8 a3 = *(const bf16x8*)&xs[48 + lr][k0 + lk * 8];
        #pragma unroll
        for (int q = 0; q < 4; ++q) {
            int o = (q >> 1) * 128 + wave * 32 + (q & 1) * 16 + lr;
            bf16x8 b = *(const bf16x8*)(Wrz + (size_t)o * 384 + k0 + lk * 8);
            accrz[0][q] = MFMA16(a0, b, accrz[0][q]);
            accrz[1][q] = MFMA16(a1, b, accrz[1][q]);
            accrz[2][q] = MFMA16(a2, b, accrz[2][q]);
            accrz[3][q] = MFMA16(a3, b, accrz[3][q]);
        }
    }

    // ---- GEMM_in: in = a @ Win^T over K=256 ----
    f32x4 accin[4][2] = {};
    #pragma unroll 2
    for (int k0 = 0; k0 < 256; k0 += 32) {
        bf16x8 a0 = *(const bf16x8*)&xs[lr][128 + k0 + lk * 8];
        bf16x8 a1 = *(const bf16x8*)&xs[16 + lr][128 + k0 + lk * 8];
        bf16x8 a2 = *(const bf16x8*)&xs[32 + lr][128 + k0 + lk * 8];
        bf16x8 a3 = *(const bf16x8*)&xs[48 + lr][128 + k0 + lk * 8];
        #pragma unroll
        for (int j = 0; j < 2; ++j) {
            int o = wave * 32 + j * 16 + lr;
            bf16x8 b = *(const bf16x8*)(Win + (size_t)o * 256 + k0 + lk * 8);
            accin[0][j] = MFMA16(a0, b, accin[0][j]);
            accin[1][j] = MFMA16(a1, b, accin[1][j]);
            accin[2][j] = MFMA16(a2, b, accin[2][j]);
            accin[3][j] = MFMA16(a3, b, accin[3][j]);
        }
    }

    // ---- GRU epilogue ----
    #pragma unroll
    for (int mf = 0; mf < 4; ++mf) {
        #pragma unroll
        for (int j = 0; j < 2; ++j) {
            int hcol = wave * 32 + j * 16 + lr;
            float brz_r = bih[hcol]       + bhh[hcol];
            float brz_z = bih[128 + hcol] + bhh[128 + hcol];
            float b_in  = bih[256 + hcol];
            float b_hn  = bhh[256 + hcol];
            #pragma unroll
            for (int r = 0; r < 4; ++r) {
                int m = mf * 16 + lk * 4 + r;
                int node = m0 + m;
                if (node < N) {
                    float rg = 1.f / (1.f + __expf(-(accrz[mf][0 + j][r] + brz_r)));
                    float zg = 1.f / (1.f + __expf(-(accrz[mf][2 + j][r] + brz_z)));
                    float ng = tanhf(accin[mf][j][r] + b_in + rg * (acchn[mf][j][r] + b_hn));
                    float hold = hv_hold[(size_t)node * 128 + hcol];
                    float hnew = (1.f - zg) * ng + zg * hold;
                    hv_out[(size_t)node * 128 + hcol] = hnew;
                    if (WRITE_BF) hv_bf[(size_t)node * 128 + hcol] = (__bf16)hnew;
                }
            }
        }
    }
}

extern "C" void kernel_launch(void* const* d_in, const int* in_sizes, int n_in,
                              void* d_out, int out_size, void* d_ws, size_t ws_size,
                              hipStream_t stream)
{
    const float* hv   = (const float*)d_in[0];
    const float* he   = (const float*)d_in[1];
    const int*   src  = (const int*)d_in[2];
    const int*   dst  = (const int*)d_in[3];
    const float* Wmsg = (const float*)d_in[4];
    const float* bmsg = (const float*)d_in[5];
    const float* Wih  = (const float*)d_in[6];
    const float* Whh  = (const float*)d_in[7];
    const float* bih  = (const float*)d_in[8];
    const float* bhh  = (const float*)d_in[9];

    const int H = 128;
    const int N = in_sizes[0] / H;
    const int E = in_sizes[2];

    // ---- workspace layout ----
    char* w = (char*)d_ws;
    __bf16* he_mean   = (__bf16*)w;  w += (size_t)N * H * 2;
    __bf16* hsrc_mean = (__bf16*)w;  w += (size_t)N * H * 2;
    __bf16* hv_bf     = (__bf16*)w;  w += (size_t)N * H * 2;
    int* degi    = (int*)w;  w += (size_t)N * 4;
    int* counter = (int*)w;  w += 4;
    int* off     = (int*)w;  w += (size_t)N * 4;
    int* cnt     = (int*)w;  w += (size_t)N * 4;
    w = (char*)(((uintptr_t)w + 15) & ~(uintptr_t)15);
    int2* pairs  = (int2*)w; w += (size_t)E * 8;
    __bf16* wmsg_bf = (__bf16*)w;                       // [2][256][384]
    __bf16* wrz_bf  = wmsg_bf + 2 * 256 * 384;          // [2][256][384]
    __bf16* win_bf  = wrz_bf  + 2 * 256 * 384;          // [2][128][256]
    __bf16* whn_bf  = win_bf  + 2 * 128 * 256;          // [2][128][128]

    hipMemsetAsync(degi, 0, ((size_t)N + 1) * 4, stream);   // degi + counter

    const int prepack_total = 2*256*384 + 2*256*384 + 2*128*256 + 2*128*128;
    const int hv8    = N * H / 8;
    const int nb_pre = (prepack_total + 255) / 256;
    const int nb_hv  = (hv8 + 255) / 256;
    const int nb_deg = (E + 255) / 256;
    k_setup<<<nb_pre + nb_hv + nb_deg, 256, 0, stream>>>(
        Wmsg, Wih, Whh, hv, dst,
        wmsg_bf, wrz_bf, win_bf, whn_bf, hv_bf, degi,
        nb_pre, nb_hv, hv8, E);

    k_alloc<<<(N + 255) / 256, 256, 0, stream>>>(degi, off, cnt, counter, N);
    k_bucket<<<(E + 255) / 256, 256, 0, stream>>>(src, dst, off, cnt, pairs, E);

    float* out = (float*)d_out;
    const int nb_f = (N + 63) / 64;

    // round 1
    k_gather_both<<<(N + 3) / 4, 256, 0, stream>>>(hv_bf, he, pairs, off, degi,
                                                   hsrc_mean, he_mean, N);
    k_fused_round<true><<<nb_f, 256, 0, stream>>>(
        hv, hv_bf, hsrc_mean, he_mean,
        wmsg_bf, bmsg, wrz_bf, win_bf, whn_bf, bih, bhh, out, N);

    // round 2 (hv_bf updated by round 1's epilogue; ordering via dispatch boundary)
    k_gather_hv<<<(N + 3) / 4, 256, 0, stream>>>(hv_bf, pairs, off, degi, hsrc_mean, N);
    k_fused_round<false><<<nb_f, 256, 0, stream>>>(
        out, hv_bf, hsrc_mean, he_mean,
        wmsg_bf + (size_t)256 * 384, bmsg + 256,
        wrz_bf + (size_t)256 * 384, win_bf + (size_t)128 * 256, whn_bf + (size_t)128 * 128,
        bih + 384, bhh + 384, out, N);
}